// Round 4
// baseline (744.799 us; speedup 1.0000x reference)
//
#include <hip/hip_runtime.h>
#include <hip/hip_fp16.h>

#define N_NODES 50000
#define N_EDGES 800000
// F_KEY_NFEAT = 64, scale = 1/sqrt(64) = 0.125
// fiber2head: head h of a 64-float row = [f0[2h], f0[2h+1], f1[6h..6h+5]]

struct alignas(16) H8 { __half h[8]; };
typedef float vfloat4 __attribute__((ext_vector_type(4)));  // native vector: OK for nontemporal builtins

// ---------------- 1. degree histograms (int atomics only) ----------------
__global__ __launch_bounds__(256) void k_hist(const int* __restrict__ ei,
                                              int* __restrict__ cnt_r,
                                              int* __restrict__ cnt_c)
{
    int e = blockIdx.x * blockDim.x + threadIdx.x;
    if (e >= N_EDGES) return;
    atomicAdd(cnt_r + ei[e], 1);
    atomicAdd(cnt_c + ei[N_EDGES + e], 1);
}

// ---------------- 2. exclusive scan, wave-shfl based, r/c passes concurrent ----------------
// block 0 scans cnt_r -> off_r, block 1 scans cnt_c -> off_c. 2 barriers per 8192-tile.
#define SCAN_T 1024
#define SCAN_I 8
__global__ __launch_bounds__(SCAN_T) void k_scan2(int* cnt_r, int* off_r,
                                                  int* cnt_c, int* off_c)
{
    int* cnt = blockIdx.x ? cnt_c : cnt_r;
    int* off = blockIdx.x ? off_c : off_r;
    __shared__ int wsum[16];
    __shared__ int carry_s;
    const int n = N_NODES;
    int wid = threadIdx.x >> 6, lane = threadIdx.x & 63;
    if (threadIdx.x == 0) carry_s = 0;
    __syncthreads();
    for (int base = 0; base < n; base += SCAN_T * SCAN_I) {
        int idx0 = base + threadIdx.x * SCAN_I;
        int v[SCAN_I];
        int sum = 0;
        #pragma unroll
        for (int j = 0; j < SCAN_I; ++j) {
            int i = idx0 + j;
            v[j] = (i < n) ? cnt[i] : 0;
            sum += v[j];
        }
        // wave-inclusive scan of per-thread sums (no barriers)
        int x = sum;
        #pragma unroll
        for (int d = 1; d < 64; d <<= 1) {
            int t = __shfl_up(x, d);
            if (lane >= d) x += t;
        }
        if (lane == 63) wsum[wid] = x;
        __syncthreads();
        if (wid == 0 && lane < 16) {
            int y = wsum[lane];
            #pragma unroll
            for (int d = 1; d < 16; d <<= 1) {
                int t = __shfl_up(y, d);
                if (lane >= d) y += t;
            }
            wsum[lane] = y;   // inclusive wave-prefix
        }
        __syncthreads();
        int wave_excl = wid ? wsum[wid - 1] : 0;
        int run = carry_s + wave_excl + (x - sum);
        #pragma unroll
        for (int j = 0; j < SCAN_I; ++j) {
            int i = idx0 + j;
            if (i < n) { off[i] = run; cnt[i] = run; }  // cnt becomes fill cursor
            run += v[j];
        }
        __syncthreads();
        if (threadIdx.x == 0) carry_s += wsum[15];
        __syncthreads();
    }
    if (threadIdx.x == 0) off[n] = carry_s;
}

// ---------------- 3. logits + exp (f16) + dual CSR fill (int atomics only) ----------------
// eid_c entries pack {edge, row} so k_out has a 2-level (not 3-level) load chain.
__global__ __launch_bounds__(256) void k_logits_fill(
    const float* __restrict__ k0, const float* __restrict__ k1,
    const float* __restrict__ q0, const float* __restrict__ q1,
    const int* __restrict__ ei, __half* __restrict__ e_buf,
    int* __restrict__ cur_r, int* __restrict__ cur_c,
    int* __restrict__ eid_r, int2* __restrict__ eid_c2)
{
    int e = blockIdx.x * blockDim.x + threadIdx.x;
    if (e >= N_EDGES) return;
    int row = ei[e];
    int col = ei[N_EDGES + e];

    // issue CSR-cursor atomics early: latency overlaps the 16 k/q loads below
    int pr = atomicAdd(cur_r + row, 1);
    int pc = atomicAdd(cur_c + col, 1);

    const vfloat4* k0v = (const vfloat4*)(k0 + (size_t)e   * 16);
    const float4*  q0v = (const float4*)(q0 + (size_t)col * 16);
    const vfloat4* k1v = (const vfloat4*)(k1 + (size_t)e   * 48);
    const float4*  q1v = (const float4*)(q1 + (size_t)col * 48);

    float acc[8];
    #pragma unroll
    for (int h = 0; h < 8; ++h) acc[h] = 0.f;

    // k rows are single-use: non-temporal so they don't evict q/e_buf from L2
    #pragma unroll
    for (int i = 0; i < 4; ++i) {
        vfloat4 kv = __builtin_nontemporal_load(k0v + i);
        float4  qv = q0v[i];
        acc[(4*i+0)/2] += kv.x * qv.x;
        acc[(4*i+1)/2] += kv.y * qv.y;
        acc[(4*i+2)/2] += kv.z * qv.z;
        acc[(4*i+3)/2] += kv.w * qv.w;
    }
    #pragma unroll
    for (int j = 0; j < 12; ++j) {
        vfloat4 kv = __builtin_nontemporal_load(k1v + j);
        float4  qv = q1v[j];
        acc[(4*j+0)/6] += kv.x * qv.x;
        acc[(4*j+1)/6] += kv.y * qv.y;
        acc[(4*j+2)/6] += kv.z * qv.z;
        acc[(4*j+3)/6] += kv.w * qv.w;
    }

    H8 pack;
    #pragma unroll
    for (int h = 0; h < 8; ++h) pack.h[h] = __float2half(__expf(acc[h] * 0.125f));
    *(H8*)(e_buf + (size_t)e * 8) = pack;

    eid_r[pr] = e;
    int2 pr2; pr2.x = e; pr2.y = row;
    eid_c2[pc] = pr2;
}

// ---------------- 4. softmax denominator reciprocal via row-CSR gather ----------------
// thread = (node, head); 8x unrolled edge loop for memory-level parallelism.
__global__ __launch_bounds__(256) void k_s(const __half* __restrict__ e_buf,
                                           const int* __restrict__ off_r,
                                           const int* __restrict__ eid_r,
                                           float* __restrict__ rs)
{
    int t = blockIdx.x * blockDim.x + threadIdx.x;
    int node = t >> 3;
    int h = t & 7;
    if (node >= N_NODES) return;
    int beg = off_r[node], end = off_r[node + 1];
    float acc = 0.f;
    int i = beg;
    for (; i + 8 <= end; i += 8) {
        float x0 = __half2float(e_buf[(size_t)eid_r[i + 0] * 8 + h]);
        float x1 = __half2float(e_buf[(size_t)eid_r[i + 1] * 8 + h]);
        float x2 = __half2float(e_buf[(size_t)eid_r[i + 2] * 8 + h]);
        float x3 = __half2float(e_buf[(size_t)eid_r[i + 3] * 8 + h]);
        float x4 = __half2float(e_buf[(size_t)eid_r[i + 4] * 8 + h]);
        float x5 = __half2float(e_buf[(size_t)eid_r[i + 5] * 8 + h]);
        float x6 = __half2float(e_buf[(size_t)eid_r[i + 6] * 8 + h]);
        float x7 = __half2float(e_buf[(size_t)eid_r[i + 7] * 8 + h]);
        acc += ((x0 + x1) + (x2 + x3)) + ((x4 + x5) + (x6 + x7));
    }
    for (; i < end; ++i) {
        acc += __half2float(e_buf[(size_t)eid_r[i] * 8 + h]);
    }
    rs[(size_t)node * 8 + h] = 1.0f / acc;   // inf only for edge-less rows, never read
}

// ---------------- 5. output via col-CSR gather: 1 wave/node, lane=feature ----------------
// int2 {e,row} -> v / e_buf / rs gathers all issue in parallel; 8 chains in flight.
__global__ __launch_bounds__(256) void k_out(
    const float* __restrict__ v0, const float* __restrict__ v1,
    const __half* __restrict__ e_buf, const float* __restrict__ rs,
    const int* __restrict__ off_c, const int2* __restrict__ eid_c2,
    float* __restrict__ out0, float* __restrict__ out1)
{
    int wave = (blockIdx.x * blockDim.x + threadIdx.x) >> 6;
    int lane = threadIdx.x & 63;
    if (wave >= N_NODES) return;
    bool is0 = lane < 16;
    int f1 = lane - 16;                       // index into the 48-float v1 row
    int head = is0 ? (lane >> 1) : (f1 / 6);
    const float* __restrict__ vbase = is0 ? (v0 + lane) : (v1 + f1);
    int vstride = is0 ? 16 : 48;

    int beg = off_c[wave], end = off_c[wave + 1];
    float acc = 0.f;
    int i = beg;
    for (; i + 8 <= end; i += 8) {
        int2 p0 = eid_c2[i + 0];
        int2 p1 = eid_c2[i + 1];
        int2 p2 = eid_c2[i + 2];
        int2 p3 = eid_c2[i + 3];
        int2 p4 = eid_c2[i + 4];
        int2 p5 = eid_c2[i + 5];
        int2 p6 = eid_c2[i + 6];
        int2 p7 = eid_c2[i + 7];
        float w0 = __builtin_nontemporal_load(vbase + (size_t)p0.x * vstride);
        float w1 = __builtin_nontemporal_load(vbase + (size_t)p1.x * vstride);
        float w2 = __builtin_nontemporal_load(vbase + (size_t)p2.x * vstride);
        float w3 = __builtin_nontemporal_load(vbase + (size_t)p3.x * vstride);
        float w4 = __builtin_nontemporal_load(vbase + (size_t)p4.x * vstride);
        float w5 = __builtin_nontemporal_load(vbase + (size_t)p5.x * vstride);
        float w6 = __builtin_nontemporal_load(vbase + (size_t)p6.x * vstride);
        float w7 = __builtin_nontemporal_load(vbase + (size_t)p7.x * vstride);
        float a0 = __half2float(e_buf[(size_t)p0.x * 8 + head]) * rs[(size_t)p0.y * 8 + head];
        float a1 = __half2float(e_buf[(size_t)p1.x * 8 + head]) * rs[(size_t)p1.y * 8 + head];
        float a2 = __half2float(e_buf[(size_t)p2.x * 8 + head]) * rs[(size_t)p2.y * 8 + head];
        float a3 = __half2float(e_buf[(size_t)p3.x * 8 + head]) * rs[(size_t)p3.y * 8 + head];
        float a4 = __half2float(e_buf[(size_t)p4.x * 8 + head]) * rs[(size_t)p4.y * 8 + head];
        float a5 = __half2float(e_buf[(size_t)p5.x * 8 + head]) * rs[(size_t)p5.y * 8 + head];
        float a6 = __half2float(e_buf[(size_t)p6.x * 8 + head]) * rs[(size_t)p6.y * 8 + head];
        float a7 = __half2float(e_buf[(size_t)p7.x * 8 + head]) * rs[(size_t)p7.y * 8 + head];
        acc += a0 * w0; acc += a1 * w1; acc += a2 * w2; acc += a3 * w3;
        acc += a4 * w4; acc += a5 * w5; acc += a6 * w6; acc += a7 * w7;
    }
    for (; i + 4 <= end; i += 4) {
        int2 p0 = eid_c2[i + 0];
        int2 p1 = eid_c2[i + 1];
        int2 p2 = eid_c2[i + 2];
        int2 p3 = eid_c2[i + 3];
        float w0 = __builtin_nontemporal_load(vbase + (size_t)p0.x * vstride);
        float w1 = __builtin_nontemporal_load(vbase + (size_t)p1.x * vstride);
        float w2 = __builtin_nontemporal_load(vbase + (size_t)p2.x * vstride);
        float w3 = __builtin_nontemporal_load(vbase + (size_t)p3.x * vstride);
        float a0 = __half2float(e_buf[(size_t)p0.x * 8 + head]) * rs[(size_t)p0.y * 8 + head];
        float a1 = __half2float(e_buf[(size_t)p1.x * 8 + head]) * rs[(size_t)p1.y * 8 + head];
        float a2 = __half2float(e_buf[(size_t)p2.x * 8 + head]) * rs[(size_t)p2.y * 8 + head];
        float a3 = __half2float(e_buf[(size_t)p3.x * 8 + head]) * rs[(size_t)p3.y * 8 + head];
        acc += a0 * w0; acc += a1 * w1; acc += a2 * w2; acc += a3 * w3;
    }
    for (; i < end; ++i) {
        int2 p0 = eid_c2[i];
        acc += __half2float(e_buf[(size_t)p0.x * 8 + head])
             * rs[(size_t)p0.y * 8 + head]
             * __builtin_nontemporal_load(vbase + (size_t)p0.x * vstride);
    }
    if (is0) out0[(size_t)wave * 16 + lane] = acc;
    else     out1[(size_t)wave * 48 + f1]   = acc;
}

extern "C" void kernel_launch(void* const* d_in, const int* in_sizes, int n_in,
                              void* d_out, int out_size, void* d_ws, size_t ws_size,
                              hipStream_t stream) {
    const float* v0 = (const float*)d_in[0];
    const float* v1 = (const float*)d_in[1];
    const float* k0 = (const float*)d_in[2];
    const float* k1 = (const float*)d_in[3];
    const float* q0 = (const float*)d_in[4];
    const float* q1 = (const float*)d_in[5];
    const int*   ei = (const int*)d_in[6];

    float* out0 = (float*)d_out;                      // N*16 floats
    float* out1 = out0 + (size_t)N_NODES * 16;        // N*48 floats

    // ---- workspace layout (bytes), total ~24.8 MB ----
    char* ws = (char*)d_ws;
    int*    cnt_r  = (int*)   (ws + 0);               // N*4     = 200,000
    int*    cnt_c  = (int*)   (ws + 200000);          // N*4     = 200,000 (adjacent: one memset)
    int*    off_r  = (int*)   (ws + 400000);          // (N+1)*4 -> pad 200,016
    int*    off_c  = (int*)   (ws + 600016);          // pad 200,016
    int*    eid_r  = (int*)   (ws + 800032);          // E*4     = 3,200,000
    int2*   eid_c2 = (int2*)  (ws + 4000032);         // E*8     = 6,400,000 (8B aligned)
    __half* e_buf  = (__half*)(ws + 10400032);        // E*8*2   = 12,800,000 (16B aligned)
    float*  rs     = (float*) (ws + 23200032);        // N*8*4   = 1,600,000

    // zero both degree arrays in one shot (adjacent)
    hipMemsetAsync(cnt_r, 0, 400000, stream);

    const int block = 256;
    const int gridE = (N_EDGES + block - 1) / block;

    k_hist<<<gridE, block, 0, stream>>>(ei, cnt_r, cnt_c);
    k_scan2<<<2, SCAN_T, 0, stream>>>(cnt_r, off_r, cnt_c, off_c);
    k_logits_fill<<<gridE, block, 0, stream>>>(k0, k1, q0, q1, ei, e_buf,
                                               cnt_r, cnt_c, eid_r, eid_c2);
    k_s<<<(N_NODES * 8 + block - 1) / block, block, 0, stream>>>(e_buf, off_r, eid_r, rs);
    k_out<<<(N_NODES * 64 + block - 1) / block, block, 0, stream>>>(
        v0, v1, e_buf, rs, off_c, eid_c2, out0, out1);
}

// Round 5
// 698.675 us; speedup vs baseline: 1.0660x; 1.0660x over previous
//
#include <hip/hip_runtime.h>
#include <hip/hip_fp16.h>

#define N_NODES 50000
#define N_EDGES 800000
// F_KEY_NFEAT = 64, scale = 1/sqrt(64) = 0.125
// fiber2head: head h of a 64-float row = [f0[2h], f0[2h+1], f1[6h..6h+5]]

struct alignas(16) H8 { __half h[8]; };

// ---------------- 1. degree histograms (int atomics only) ----------------
__global__ __launch_bounds__(256) void k_hist(const int* __restrict__ ei,
                                              int* __restrict__ cnt_r,
                                              int* __restrict__ cnt_c)
{
    int e = blockIdx.x * blockDim.x + threadIdx.x;
    if (e >= N_EDGES) return;
    atomicAdd(cnt_r + ei[e], 1);
    atomicAdd(cnt_c + ei[N_EDGES + e], 1);
}

// ---------------- 2. exclusive scan, wave-shfl based, r/c passes concurrent ----------------
// block 0 scans cnt_r -> off_r, block 1 scans cnt_c -> off_c. 2 barriers per 8192-tile.
#define SCAN_T 1024
#define SCAN_I 8
__global__ __launch_bounds__(SCAN_T) void k_scan2(int* cnt_r, int* off_r,
                                                  int* cnt_c, int* off_c)
{
    int* cnt = blockIdx.x ? cnt_c : cnt_r;
    int* off = blockIdx.x ? off_c : off_r;
    __shared__ int wsum[16];
    __shared__ int carry_s;
    const int n = N_NODES;
    int wid = threadIdx.x >> 6, lane = threadIdx.x & 63;
    if (threadIdx.x == 0) carry_s = 0;
    __syncthreads();
    for (int base = 0; base < n; base += SCAN_T * SCAN_I) {
        int idx0 = base + threadIdx.x * SCAN_I;
        int v[SCAN_I];
        int sum = 0;
        #pragma unroll
        for (int j = 0; j < SCAN_I; ++j) {
            int i = idx0 + j;
            v[j] = (i < n) ? cnt[i] : 0;
            sum += v[j];
        }
        // wave-inclusive scan of per-thread sums (no barriers)
        int x = sum;
        #pragma unroll
        for (int d = 1; d < 64; d <<= 1) {
            int t = __shfl_up(x, d);
            if (lane >= d) x += t;
        }
        if (lane == 63) wsum[wid] = x;
        __syncthreads();
        if (wid == 0 && lane < 16) {
            int y = wsum[lane];
            #pragma unroll
            for (int d = 1; d < 16; d <<= 1) {
                int t = __shfl_up(y, d);
                if (lane >= d) y += t;
            }
            wsum[lane] = y;   // inclusive wave-prefix
        }
        __syncthreads();
        int wave_excl = wid ? wsum[wid - 1] : 0;
        int run = carry_s + wave_excl + (x - sum);
        #pragma unroll
        for (int j = 0; j < SCAN_I; ++j) {
            int i = idx0 + j;
            if (i < n) { off[i] = run; cnt[i] = run; }  // cnt becomes fill cursor
            run += v[j];
        }
        __syncthreads();
        if (threadIdx.x == 0) carry_s += wsum[15];
        __syncthreads();
    }
    if (threadIdx.x == 0) off[n] = carry_s;
}

// ---------------- 3. logits + exp (f16), e-values written in COL-CSR order ----------------
// e_c[pc]   : 8 halfs per col-CSR slot  -> k_out reads them as a contiguous stream
// eid_c2[pc]: {edge, row}               -> k_out's v / rs addresses, 1 load level
// xlink_r[pr]: pc                       -> k_s finds its row's e-values (2-level, as before)
__global__ __launch_bounds__(256) void k_logits_fill(
    const float* __restrict__ k0, const float* __restrict__ k1,
    const float* __restrict__ q0, const float* __restrict__ q1,
    const int* __restrict__ ei,
    int* __restrict__ cur_r, int* __restrict__ cur_c,
    int* __restrict__ xlink_r, int2* __restrict__ eid_c2,
    H8* __restrict__ e_c)
{
    int e = blockIdx.x * blockDim.x + threadIdx.x;
    if (e >= N_EDGES) return;
    int row = ei[e];
    int col = ei[N_EDGES + e];

    // issue CSR-cursor atomics early: latency overlaps the 16 k/q loads below
    int pr = atomicAdd(cur_r + row, 1);
    int pc = atomicAdd(cur_c + col, 1);

    const float4* k0v = (const float4*)(k0 + (size_t)e   * 16);
    const float4* q0v = (const float4*)(q0 + (size_t)col * 16);
    const float4* k1v = (const float4*)(k1 + (size_t)e   * 48);
    const float4* q1v = (const float4*)(q1 + (size_t)col * 48);

    float acc[8];
    #pragma unroll
    for (int h = 0; h < 8; ++h) acc[h] = 0.f;

    #pragma unroll
    for (int i = 0; i < 4; ++i) {
        float4 kv = k0v[i];
        float4 qv = q0v[i];
        acc[(4*i+0)/2] += kv.x * qv.x;
        acc[(4*i+1)/2] += kv.y * qv.y;
        acc[(4*i+2)/2] += kv.z * qv.z;
        acc[(4*i+3)/2] += kv.w * qv.w;
    }
    #pragma unroll
    for (int j = 0; j < 12; ++j) {
        float4 kv = k1v[j];
        float4 qv = q1v[j];
        acc[(4*j+0)/6] += kv.x * qv.x;
        acc[(4*j+1)/6] += kv.y * qv.y;
        acc[(4*j+2)/6] += kv.z * qv.z;
        acc[(4*j+3)/6] += kv.w * qv.w;
    }

    H8 pack;
    #pragma unroll
    for (int h = 0; h < 8; ++h) pack.h[h] = __float2half(__expf(acc[h] * 0.125f));

    e_c[pc] = pack;                 // 16B scatter
    int2 pr2; pr2.x = e; pr2.y = row;
    eid_c2[pc] = pr2;               // 8B scatter
    xlink_r[pr] = pc;               // 4B scatter
}

// ---------------- 4. softmax denominator reciprocal via row-CSR gather ----------------
// thread = (node, head); 8x unrolled; gathers e_c via xlink (same 2-level as before).
__global__ __launch_bounds__(256) void k_s(const __half* __restrict__ e_half,
                                           const int* __restrict__ off_r,
                                           const int* __restrict__ xlink_r,
                                           float* __restrict__ rs)
{
    int t = blockIdx.x * blockDim.x + threadIdx.x;
    int node = t >> 3;
    int h = t & 7;
    if (node >= N_NODES) return;
    int beg = off_r[node], end = off_r[node + 1];
    float acc = 0.f;
    int i = beg;
    for (; i + 8 <= end; i += 8) {
        float x0 = __half2float(e_half[(size_t)xlink_r[i + 0] * 8 + h]);
        float x1 = __half2float(e_half[(size_t)xlink_r[i + 1] * 8 + h]);
        float x2 = __half2float(e_half[(size_t)xlink_r[i + 2] * 8 + h]);
        float x3 = __half2float(e_half[(size_t)xlink_r[i + 3] * 8 + h]);
        float x4 = __half2float(e_half[(size_t)xlink_r[i + 4] * 8 + h]);
        float x5 = __half2float(e_half[(size_t)xlink_r[i + 5] * 8 + h]);
        float x6 = __half2float(e_half[(size_t)xlink_r[i + 6] * 8 + h]);
        float x7 = __half2float(e_half[(size_t)xlink_r[i + 7] * 8 + h]);
        acc += ((x0 + x1) + (x2 + x3)) + ((x4 + x5) + (x6 + x7));
    }
    for (; i < end; ++i) {
        acc += __half2float(e_half[(size_t)xlink_r[i] * 8 + h]);
    }
    rs[(size_t)node * 8 + h] = 1.0f / acc;   // inf only for edge-less rows, never read
}

// ---------------- 5. output via col-CSR gather: 1 wave/node, lane=feature ----------------
// e-values stream contiguously (e_half[i*8+head]); only v and rs are gathered.
__global__ __launch_bounds__(256) void k_out(
    const float* __restrict__ v0, const float* __restrict__ v1,
    const __half* __restrict__ e_half, const float* __restrict__ rs,
    const int* __restrict__ off_c, const int2* __restrict__ eid_c2,
    float* __restrict__ out0, float* __restrict__ out1)
{
    int wave = (blockIdx.x * blockDim.x + threadIdx.x) >> 6;
    int lane = threadIdx.x & 63;
    if (wave >= N_NODES) return;
    bool is0 = lane < 16;
    int f1 = lane - 16;                       // index into the 48-float v1 row
    int head = is0 ? (lane >> 1) : (f1 / 6);
    const float* __restrict__ vbase = is0 ? (v0 + lane) : (v1 + f1);
    int vstride = is0 ? 16 : 48;

    int beg = off_c[wave], end = off_c[wave + 1];
    float acc = 0.f;
    int i = beg;
    for (; i + 8 <= end; i += 8) {
        int2 p0 = eid_c2[i + 0];
        int2 p1 = eid_c2[i + 1];
        int2 p2 = eid_c2[i + 2];
        int2 p3 = eid_c2[i + 3];
        int2 p4 = eid_c2[i + 4];
        int2 p5 = eid_c2[i + 5];
        int2 p6 = eid_c2[i + 6];
        int2 p7 = eid_c2[i + 7];
        float ev0 = __half2float(e_half[(size_t)(i + 0) * 8 + head]);
        float ev1 = __half2float(e_half[(size_t)(i + 1) * 8 + head]);
        float ev2 = __half2float(e_half[(size_t)(i + 2) * 8 + head]);
        float ev3 = __half2float(e_half[(size_t)(i + 3) * 8 + head]);
        float ev4 = __half2float(e_half[(size_t)(i + 4) * 8 + head]);
        float ev5 = __half2float(e_half[(size_t)(i + 5) * 8 + head]);
        float ev6 = __half2float(e_half[(size_t)(i + 6) * 8 + head]);
        float ev7 = __half2float(e_half[(size_t)(i + 7) * 8 + head]);
        float w0 = __builtin_nontemporal_load(vbase + (size_t)p0.x * vstride);
        float w1 = __builtin_nontemporal_load(vbase + (size_t)p1.x * vstride);
        float w2 = __builtin_nontemporal_load(vbase + (size_t)p2.x * vstride);
        float w3 = __builtin_nontemporal_load(vbase + (size_t)p3.x * vstride);
        float w4 = __builtin_nontemporal_load(vbase + (size_t)p4.x * vstride);
        float w5 = __builtin_nontemporal_load(vbase + (size_t)p5.x * vstride);
        float w6 = __builtin_nontemporal_load(vbase + (size_t)p6.x * vstride);
        float w7 = __builtin_nontemporal_load(vbase + (size_t)p7.x * vstride);
        float a0 = ev0 * rs[(size_t)p0.y * 8 + head];
        float a1 = ev1 * rs[(size_t)p1.y * 8 + head];
        float a2 = ev2 * rs[(size_t)p2.y * 8 + head];
        float a3 = ev3 * rs[(size_t)p3.y * 8 + head];
        float a4 = ev4 * rs[(size_t)p4.y * 8 + head];
        float a5 = ev5 * rs[(size_t)p5.y * 8 + head];
        float a6 = ev6 * rs[(size_t)p6.y * 8 + head];
        float a7 = ev7 * rs[(size_t)p7.y * 8 + head];
        acc += a0 * w0; acc += a1 * w1; acc += a2 * w2; acc += a3 * w3;
        acc += a4 * w4; acc += a5 * w5; acc += a6 * w6; acc += a7 * w7;
    }
    for (; i + 4 <= end; i += 4) {
        int2 p0 = eid_c2[i + 0];
        int2 p1 = eid_c2[i + 1];
        int2 p2 = eid_c2[i + 2];
        int2 p3 = eid_c2[i + 3];
        float ev0 = __half2float(e_half[(size_t)(i + 0) * 8 + head]);
        float ev1 = __half2float(e_half[(size_t)(i + 1) * 8 + head]);
        float ev2 = __half2float(e_half[(size_t)(i + 2) * 8 + head]);
        float ev3 = __half2float(e_half[(size_t)(i + 3) * 8 + head]);
        float w0 = __builtin_nontemporal_load(vbase + (size_t)p0.x * vstride);
        float w1 = __builtin_nontemporal_load(vbase + (size_t)p1.x * vstride);
        float w2 = __builtin_nontemporal_load(vbase + (size_t)p2.x * vstride);
        float w3 = __builtin_nontemporal_load(vbase + (size_t)p3.x * vstride);
        float a0 = ev0 * rs[(size_t)p0.y * 8 + head];
        float a1 = ev1 * rs[(size_t)p1.y * 8 + head];
        float a2 = ev2 * rs[(size_t)p2.y * 8 + head];
        float a3 = ev3 * rs[(size_t)p3.y * 8 + head];
        acc += a0 * w0; acc += a1 * w1; acc += a2 * w2; acc += a3 * w3;
    }
    for (; i < end; ++i) {
        int2 p0 = eid_c2[i];
        acc += __half2float(e_half[(size_t)i * 8 + head])
             * rs[(size_t)p0.y * 8 + head]
             * __builtin_nontemporal_load(vbase + (size_t)p0.x * vstride);
    }
    if (is0) out0[(size_t)wave * 16 + lane] = acc;
    else     out1[(size_t)wave * 48 + f1]   = acc;
}

extern "C" void kernel_launch(void* const* d_in, const int* in_sizes, int n_in,
                              void* d_out, int out_size, void* d_ws, size_t ws_size,
                              hipStream_t stream) {
    const float* v0 = (const float*)d_in[0];
    const float* v1 = (const float*)d_in[1];
    const float* k0 = (const float*)d_in[2];
    const float* k1 = (const float*)d_in[3];
    const float* q0 = (const float*)d_in[4];
    const float* q1 = (const float*)d_in[5];
    const int*   ei = (const int*)d_in[6];

    float* out0 = (float*)d_out;                      // N*16 floats
    float* out1 = out0 + (size_t)N_NODES * 16;        // N*48 floats

    // ---- workspace layout (bytes), total ~24.8 MB (same as previous passing run) ----
    char* ws = (char*)d_ws;
    int*    cnt_r   = (int*)   (ws + 0);              // N*4     = 200,000
    int*    cnt_c   = (int*)   (ws + 200000);         // N*4     = 200,000 (adjacent: one memset)
    int*    off_r   = (int*)   (ws + 400000);         // (N+1)*4 -> pad 200,016
    int*    off_c   = (int*)   (ws + 600016);         // pad 200,016
    int*    xlink_r = (int*)   (ws + 800032);         // E*4     = 3,200,000
    int2*   eid_c2  = (int2*)  (ws + 4000032);        // E*8     = 6,400,000 (8B aligned)
    H8*     e_c     = (H8*)    (ws + 10400032);       // E*16    = 12,800,000 (16B aligned)
    float*  rs      = (float*) (ws + 23200032);       // N*8*4   = 1,600,000

    // zero both degree arrays in one shot (adjacent)
    hipMemsetAsync(cnt_r, 0, 400000, stream);

    const int block = 256;
    const int gridE = (N_EDGES + block - 1) / block;

    k_hist<<<gridE, block, 0, stream>>>(ei, cnt_r, cnt_c);
    k_scan2<<<2, SCAN_T, 0, stream>>>(cnt_r, off_r, cnt_c, off_c);
    k_logits_fill<<<gridE, block, 0, stream>>>(k0, k1, q0, q1, ei,
                                               cnt_r, cnt_c, xlink_r, eid_c2, e_c);
    k_s<<<(N_NODES * 8 + block - 1) / block, block, 0, stream>>>(
        (const __half*)e_c, off_r, xlink_r, rs);
    k_out<<<(N_NODES * 64 + block - 1) / block, block, 0, stream>>>(
        v0, v1, (const __half*)e_c, rs, off_c, eid_c2, out0, out1);
}